// Round 1
// baseline (2678.484 us; speedup 1.0000x reference)
//
#include <hip/hip_runtime.h>
#include <hip/hip_bf16.h>

#define N_NODES 100000
#define N_EDGES 800000
#define D 128
#define NT 16   // nodes per block in fused kernel

// ---------------- degree ----------------
__global__ void deg_kernel(const int* __restrict__ dst, float* __restrict__ deg) {
    int e = blockIdx.x * blockDim.x + threadIdx.x;
    if (e < N_EDGES) atomicAdd(&deg[dst[e]], 1.0f);
}

__global__ void invdeg_kernel(float* __restrict__ deg) {
    int n = blockIdx.x * blockDim.x + threadIdx.x;
    if (n < N_NODES) deg[n] = 1.0f / fmaxf(deg[n], 1.0f);
}

// ---------------- scatter-add aggregation ----------------
// one 64-lane wave per edge; each lane handles 2 consecutive floats (float2)
__global__ __launch_bounds__(256) void scatter_kernel(
    const float* __restrict__ x, const int* __restrict__ src,
    const int* __restrict__ dst, float* __restrict__ agg)
{
    int tid = blockIdx.x * blockDim.x + threadIdx.x;
    int e = tid >> 6;
    int lane = tid & 63;
    if (e >= N_EDGES) return;
    int s = src[e];
    int d = dst[e];
    const float2* xr = (const float2*)(x + (size_t)s * D);
    float2 v = xr[lane];
    float* ar = agg + (size_t)d * D + lane * 2;
    atomicAdd(ar, v.x);
    atomicAdd(ar + 1, v.y);
}

// ---------------- fused: h = (agg*inv_deg)@Wl^T + bl + x@Wr^T; LN; ReLU; +res ----------------
// block = 256 threads, NT=16 nodes per block. out may alias agg (block owns its rows).
__global__ __launch_bounds__(256) void fused_kernel(
    const float* __restrict__ x,        // [N,D] layer input
    const float* __restrict__ agg,      // [N,D] neighbor sums
    const float* __restrict__ inv_deg,  // [N]
    const float* __restrict__ Wl,       // [D,D]  Wl[j][k]
    const float* __restrict__ bl,       // [D]
    const float* __restrict__ Wr,       // [D,D]
    const float* __restrict__ gamma_,   // [D]
    const float* __restrict__ beta_,    // [D]
    float* __restrict__ out,            // [N,D]
    int addResidual)
{
    __shared__ float mean_s[NT][D];
    __shared__ float x_s[NT][D];
    __shared__ float h_s[NT][D + 1];
    __shared__ float mu_s[NT], rs_s[NT];

    int t = threadIdx.x;
    int base = blockIdx.x * NT;

    // stage 16 node rows of x and mean = agg*inv_deg (coalesced: 256 threads x 8)
    for (int i = 0; i < 8; ++i) {
        int idx = i * 256 + t;
        int n = idx >> 7, j = idx & 127;
        int node = base + n;
        float xv = x[(size_t)node * D + j];
        float av = agg[(size_t)node * D + j];
        float id = inv_deg[node];
        x_s[n][j] = xv;
        mean_s[n][j] = av * id;
    }
    __syncthreads();

    // compute: thread (j = t&127, g = t>>7) accumulates 8 nodes (g*8 .. g*8+7)
    int j = t & 127, g = t >> 7;
    float acc[8];
#pragma unroll
    for (int q = 0; q < 8; ++q) acc[q] = 0.f;
    const float4* wl4 = (const float4*)(Wl + (size_t)j * D);
    const float4* wr4 = (const float4*)(Wr + (size_t)j * D);
#pragma unroll 4
    for (int k4 = 0; k4 < D / 4; ++k4) {
        float4 a = wl4[k4];
        float4 b = wr4[k4];
        int k = k4 * 4;
#pragma unroll
        for (int q = 0; q < 8; ++q) {
            int n = g * 8 + q;
            const float4 m4 = *(const float4*)&mean_s[n][k];
            const float4 x4 = *(const float4*)&x_s[n][k];
            acc[q] += m4.x * a.x + m4.y * a.y + m4.z * a.z + m4.w * a.w
                    + x4.x * b.x + x4.y * b.y + x4.z * b.z + x4.w * b.w;
        }
    }
    float bj = bl[j];
#pragma unroll
    for (int q = 0; q < 8; ++q) h_s[g * 8 + q][j] = acc[q] + bj;
    __syncthreads();

    // LayerNorm stats: 16 threads per node, shfl-reduce within 16-lane groups
    {
        int n = t >> 4, r = t & 15;
        float s = 0.f, ss = 0.f;
#pragma unroll
        for (int i = 0; i < 8; ++i) {
            float v = h_s[n][r + i * 16];
            s += v; ss += v * v;
        }
#pragma unroll
        for (int m = 8; m >= 1; m >>= 1) {
            s  += __shfl_xor(s,  m, 16);
            ss += __shfl_xor(ss, m, 16);
        }
        if (r == 0) {
            float mu = s * (1.f / 128.f);
            float var = ss * (1.f / 128.f) - mu * mu;
            mu_s[n] = mu;
            rs_s[n] = rsqrtf(var + 1e-5f);
        }
    }
    __syncthreads();

    // normalize + relu + residual, coalesced write
    for (int i = 0; i < 8; ++i) {
        int idx = i * 256 + t;
        int n = idx >> 7, jj = idx & 127;
        int node = base + n;
        float v = (h_s[n][jj] - mu_s[n]) * rs_s[n] * gamma_[jj] + beta_[jj];
        v = fmaxf(v, 0.f);
        if (addResidual) v += x_s[n][jj];
        out[(size_t)node * D + jj] = v;
    }
}

extern "C" void kernel_launch(void* const* d_in, const int* in_sizes, int n_in,
                              void* d_out, int out_size, void* d_ws, size_t ws_size,
                              hipStream_t stream) {
    const float* x0  = (const float*)d_in[0];
    const int*   ei  = (const int*)d_in[1];
    const float* Wl  = (const float*)d_in[2];
    const float* bl  = (const float*)d_in[3];
    const float* Wr  = (const float*)d_in[4];
    const float* gam = (const float*)d_in[5];
    const float* bet = (const float*)d_in[6];
    float* out = (float*)d_out;

    const int* src = ei;
    const int* dst = ei + N_EDGES;

    float* ws   = (float*)d_ws;
    float* deg  = ws;                 // N floats -> becomes inv_deg in place
    float* bufA = ws + 131072;        // N*D floats (51.2 MB)

    const size_t rowBytes = (size_t)N_NODES * D * sizeof(float);

    // degrees -> inv_deg (recomputed every call; deterministic work)
    hipMemsetAsync(deg, 0, N_NODES * sizeof(float), stream);
    deg_kernel<<<(N_EDGES + 255) / 256, 256, 0, stream>>>(dst, deg);
    invdeg_kernel<<<(N_NODES + 255) / 256, 256, 0, stream>>>(deg);

    const int scatterBlocks = (N_EDGES * 64) / 256;
    const int fusedBlocks = N_NODES / NT;   // 100000/16 = 6250 exact

    // ---- layer 0: x0 (d_in) -> bufA ----
    hipMemsetAsync(bufA, 0, rowBytes, stream);
    scatter_kernel<<<scatterBlocks, 256, 0, stream>>>(x0, src, dst, bufA);
    fused_kernel<<<fusedBlocks, 256, 0, stream>>>(
        x0, bufA, deg, Wl, bl, Wr, gam, bet, bufA, 0);

    // ---- layer 1: bufA -> d_out ----
    hipMemsetAsync(out, 0, rowBytes, stream);
    scatter_kernel<<<scatterBlocks, 256, 0, stream>>>(bufA, src, dst, out);
    fused_kernel<<<fusedBlocks, 256, 0, stream>>>(
        bufA, out, deg, Wl + D * D, bl + D, Wr + D * D, gam + D, bet + D, out, 1);

    // ---- layer 2: d_out -> d_out (agg in bufA) ----
    hipMemsetAsync(bufA, 0, rowBytes, stream);
    scatter_kernel<<<scatterBlocks, 256, 0, stream>>>(out, src, dst, bufA);
    fused_kernel<<<fusedBlocks, 256, 0, stream>>>(
        out, bufA, deg, Wl + 2 * D * D, bl + 2 * D, Wr + 2 * D * D,
        gam + 2 * D, bet + 2 * D, out, 1);
}

// Round 2
// 895.549 us; speedup vs baseline: 2.9909x; 2.9909x over previous
//
#include <hip/hip_runtime.h>
#include <hip/hip_bf16.h>

#define N_NODES 100000
#define N_EDGES 800000
#define D 128
#define NT 16   // nodes per block in fused kernel

// ================= CSR build =================

__global__ __launch_bounds__(256) void hist_kernel(
    const int* __restrict__ dst, int* __restrict__ cnt)
{
    int e = blockIdx.x * blockDim.x + threadIdx.x;
    if (e < N_EDGES) atomicAdd(&cnt[dst[e]], 1);
}

// per-block reduce of 256 degrees -> bsum[block]
__global__ __launch_bounds__(256) void scan_reduce(
    const int* __restrict__ degi, int* __restrict__ bsum)
{
    __shared__ int sh[256];
    int t = threadIdx.x;
    int i = blockIdx.x * 256 + t;
    sh[t] = (i < N_NODES) ? degi[i] : 0;
    __syncthreads();
    for (int off = 128; off >= 1; off >>= 1) {
        if (t < off) sh[t] += sh[t + off];
        __syncthreads();
    }
    if (t == 0) bsum[blockIdx.x] = sh[0];
}

// single block: exclusive scan of nb block sums
__global__ __launch_bounds__(512) void scan_bsums(
    const int* __restrict__ bsum, int* __restrict__ boff, int nb)
{
    __shared__ int sh[512];
    int t = threadIdx.x;
    int v = (t < nb) ? bsum[t] : 0;
    sh[t] = v;
    __syncthreads();
    for (int off = 1; off < 512; off <<= 1) {
        int add = (t >= off) ? sh[t - off] : 0;
        __syncthreads();
        sh[t] += add;
        __syncthreads();
    }
    if (t < nb) boff[t] = sh[t] - v;   // exclusive
}

// per-block exclusive scan of 256 degrees + block offset -> row_ptr
__global__ __launch_bounds__(256) void scan_write(
    const int* __restrict__ degi, const int* __restrict__ boff,
    int* __restrict__ row_ptr)
{
    __shared__ int sh[256];
    int t = threadIdx.x;
    int i = blockIdx.x * 256 + t;
    int v = (i < N_NODES) ? degi[i] : 0;
    sh[t] = v;
    __syncthreads();
    for (int off = 1; off < 256; off <<= 1) {
        int add = (t >= off) ? sh[t - off] : 0;
        __syncthreads();
        sh[t] += add;
        __syncthreads();
    }
    if (i < N_NODES) row_ptr[i] = boff[blockIdx.x] + sh[t] - v;
    if (blockIdx.x == 0 && t == 0) row_ptr[N_NODES] = N_EDGES;
}

__global__ __launch_bounds__(256) void fill_kernel(
    const int* __restrict__ src, const int* __restrict__ dst,
    const int* __restrict__ row_ptr, int* __restrict__ cnt,
    int* __restrict__ esrc)
{
    int e = blockIdx.x * blockDim.x + threadIdx.x;
    if (e < N_EDGES) {
        int d = dst[e];
        int p = row_ptr[d] + atomicAdd(&cnt[d], 1);
        esrc[p] = src[e];
    }
}

// ================= gather aggregation: one wave per node =================
__global__ __launch_bounds__(256) void agg_kernel(
    const float* __restrict__ x, const int* __restrict__ row_ptr,
    const int* __restrict__ esrc, float* __restrict__ mean)
{
    int tid = blockIdx.x * blockDim.x + threadIdx.x;
    int node = tid >> 6;
    int lane = tid & 63;
    if (node >= N_NODES) return;
    int beg = row_ptr[node], end = row_ptr[node + 1];
    float ax = 0.f, ay = 0.f;
    int i = beg;
    // 4-deep MLP: independent gathers in flight
    for (; i + 4 <= end; i += 4) {
        int s0 = esrc[i], s1 = esrc[i + 1], s2 = esrc[i + 2], s3 = esrc[i + 3];
        float2 v0 = *(const float2*)(x + (size_t)s0 * D + lane * 2);
        float2 v1 = *(const float2*)(x + (size_t)s1 * D + lane * 2);
        float2 v2 = *(const float2*)(x + (size_t)s2 * D + lane * 2);
        float2 v3 = *(const float2*)(x + (size_t)s3 * D + lane * 2);
        ax += v0.x + v1.x + v2.x + v3.x;
        ay += v0.y + v1.y + v2.y + v3.y;
    }
    for (; i < end; ++i) {
        int s = esrc[i];
        float2 v = *(const float2*)(x + (size_t)s * D + lane * 2);
        ax += v.x; ay += v.y;
    }
    float sc = 1.0f / fmaxf((float)(end - beg), 1.0f);
    *(float2*)(mean + (size_t)node * D + lane * 2) = make_float2(ax * sc, ay * sc);
}

// ========== fused: h = mean@Wl^T + bl + x@Wr^T; LN; ReLU; +res ==========
// block = 256 threads, NT=16 nodes per block. out may alias mean or x (block owns its rows).
__global__ __launch_bounds__(256) void fused_kernel(
    const float* __restrict__ x,        // [N,D] layer input
    const float* __restrict__ mean,     // [N,D] mean-aggregated neighbors
    const float* __restrict__ Wl,       // [D,D]  Wl[j][k]
    const float* __restrict__ bl,       // [D]
    const float* __restrict__ Wr,       // [D,D]
    const float* __restrict__ gamma_,   // [D]
    const float* __restrict__ beta_,    // [D]
    float* __restrict__ out,            // [N,D]
    int addResidual)
{
    __shared__ float mean_s[NT][D];
    __shared__ float x_s[NT][D];
    __shared__ float h_s[NT][D + 1];
    __shared__ float mu_s[NT], rs_s[NT];

    int t = threadIdx.x;
    int base = blockIdx.x * NT;

    for (int i = 0; i < 8; ++i) {
        int idx = i * 256 + t;
        int n = idx >> 7, j = idx & 127;
        int node = base + n;
        x_s[n][j] = x[(size_t)node * D + j];
        mean_s[n][j] = mean[(size_t)node * D + j];
    }
    __syncthreads();

    int j = t & 127, g = t >> 7;
    float acc[8];
#pragma unroll
    for (int q = 0; q < 8; ++q) acc[q] = 0.f;
    const float4* wl4 = (const float4*)(Wl + (size_t)j * D);
    const float4* wr4 = (const float4*)(Wr + (size_t)j * D);
#pragma unroll 4
    for (int k4 = 0; k4 < D / 4; ++k4) {
        float4 a = wl4[k4];
        float4 b = wr4[k4];
        int k = k4 * 4;
#pragma unroll
        for (int q = 0; q < 8; ++q) {
            int n = g * 8 + q;
            const float4 m4 = *(const float4*)&mean_s[n][k];
            const float4 x4 = *(const float4*)&x_s[n][k];
            acc[q] += m4.x * a.x + m4.y * a.y + m4.z * a.z + m4.w * a.w
                    + x4.x * b.x + x4.y * b.y + x4.z * b.z + x4.w * b.w;
        }
    }
    float bj = bl[j];
#pragma unroll
    for (int q = 0; q < 8; ++q) h_s[g * 8 + q][j] = acc[q] + bj;
    __syncthreads();

    {
        int n = t >> 4, r = t & 15;
        float s = 0.f, ss = 0.f;
#pragma unroll
        for (int i = 0; i < 8; ++i) {
            float v = h_s[n][r + i * 16];
            s += v; ss += v * v;
        }
#pragma unroll
        for (int m = 8; m >= 1; m >>= 1) {
            s  += __shfl_xor(s,  m, 16);
            ss += __shfl_xor(ss, m, 16);
        }
        if (r == 0) {
            float mu = s * (1.f / 128.f);
            float var = ss * (1.f / 128.f) - mu * mu;
            mu_s[n] = mu;
            rs_s[n] = rsqrtf(var + 1e-5f);
        }
    }
    __syncthreads();

    for (int i = 0; i < 8; ++i) {
        int idx = i * 256 + t;
        int n = idx >> 7, jj = idx & 127;
        int node = base + n;
        float v = (h_s[n][jj] - mu_s[n]) * rs_s[n] * gamma_[jj] + beta_[jj];
        v = fmaxf(v, 0.f);
        if (addResidual) v += x_s[n][jj];
        out[(size_t)node * D + jj] = v;
    }
}

extern "C" void kernel_launch(void* const* d_in, const int* in_sizes, int n_in,
                              void* d_out, int out_size, void* d_ws, size_t ws_size,
                              hipStream_t stream) {
    const float* x0  = (const float*)d_in[0];
    const int*   ei  = (const int*)d_in[1];
    const float* Wl  = (const float*)d_in[2];
    const float* bl  = (const float*)d_in[3];
    const float* Wr  = (const float*)d_in[4];
    const float* gam = (const float*)d_in[5];
    const float* bet = (const float*)d_in[6];
    float* out = (float*)d_out;

    const int* src = ei;
    const int* dst = ei + N_EDGES;

    // ---- workspace layout (ints then float buffer, 256B-aligned tail) ----
    int* rp   = (int*)d_ws;            // 100001 (padded to 100352)
    int* cnt  = rp + 100352;           // 100000 (padded to 100352)
    int* bsum = cnt + 100352;          // 512
    int* boff = bsum + 512;            // 512
    int* esrc = boff + 512;            // 800000
    float* W  = (float*)(esrc + 800000);  // N*D floats

    const int nbScan = (N_NODES + 255) / 256;   // 391
    const int nbEdge = (N_EDGES + 255) / 256;   // 3125
    const int aggBlocks = (N_NODES * 64 + 255) / 256;  // 25000
    const int fusedBlocks = N_NODES / NT;       // 6250

    // ---- CSR build (once per call) ----
    hipMemsetAsync(cnt, 0, N_NODES * sizeof(int), stream);
    hist_kernel<<<nbEdge, 256, 0, stream>>>(dst, cnt);
    scan_reduce<<<nbScan, 256, 0, stream>>>(cnt, bsum);
    scan_bsums<<<1, 512, 0, stream>>>(bsum, boff, nbScan);
    scan_write<<<nbScan, 256, 0, stream>>>(cnt, boff, rp);
    hipMemsetAsync(cnt, 0, N_NODES * sizeof(int), stream);
    fill_kernel<<<nbEdge, 256, 0, stream>>>(src, dst, rp, cnt, esrc);

    // ---- layer 0: x0 -> W ----
    agg_kernel<<<aggBlocks, 256, 0, stream>>>(x0, rp, esrc, W);
    fused_kernel<<<fusedBlocks, 256, 0, stream>>>(
        x0, W, Wl, bl, Wr, gam, bet, W, 0);

    // ---- layer 1: W -> out ----
    agg_kernel<<<aggBlocks, 256, 0, stream>>>(W, rp, esrc, out);
    fused_kernel<<<fusedBlocks, 256, 0, stream>>>(
        W, out, Wl + D * D, bl + D, Wr + D * D, gam + D, bet + D, out, 1);

    // ---- layer 2: out -> out (mean in W) ----
    agg_kernel<<<aggBlocks, 256, 0, stream>>>(out, rp, esrc, W);
    fused_kernel<<<fusedBlocks, 256, 0, stream>>>(
        out, W, Wl + 2 * D * D, bl + 2 * D, Wr + 2 * D * D,
        gam + 2 * D, bet + 2 * D, out, 1);
}

// Round 3
// 481.237 us; speedup vs baseline: 5.5658x; 1.8609x over previous
//
#include <hip/hip_runtime.h>
#include <hip/hip_bf16.h>

#define N_NODES 100000
#define N_EDGES 800000
#define D 128
#define K2 256     // concat [mean | x] K dimension
#define MT 32      // nodes per block in fused kernel

typedef __attribute__((ext_vector_type(8))) short bf16x8;
typedef __attribute__((ext_vector_type(4))) float f32x4;

__device__ __forceinline__ unsigned short f2bf(float f) {
    union { float f; unsigned u; } c; c.f = f;
    unsigned u = c.u;
    return (unsigned short)((u + 0x7fffu + ((u >> 16) & 1u)) >> 16);
}

// ================= CSR build =================

__global__ __launch_bounds__(256) void hist_kernel(
    const int* __restrict__ dst, int* __restrict__ cnt)
{
    int e = blockIdx.x * blockDim.x + threadIdx.x;
    if (e < N_EDGES) atomicAdd(&cnt[dst[e]], 1);
}

__global__ __launch_bounds__(256) void scan_reduce(
    const int* __restrict__ degi, int* __restrict__ bsum)
{
    __shared__ int sh[256];
    int t = threadIdx.x;
    int i = blockIdx.x * 256 + t;
    sh[t] = (i < N_NODES) ? degi[i] : 0;
    __syncthreads();
    for (int off = 128; off >= 1; off >>= 1) {
        if (t < off) sh[t] += sh[t + off];
        __syncthreads();
    }
    if (t == 0) bsum[blockIdx.x] = sh[0];
}

__global__ __launch_bounds__(512) void scan_bsums(
    const int* __restrict__ bsum, int* __restrict__ boff, int nb)
{
    __shared__ int sh[512];
    int t = threadIdx.x;
    int v = (t < nb) ? bsum[t] : 0;
    sh[t] = v;
    __syncthreads();
    for (int off = 1; off < 512; off <<= 1) {
        int add = (t >= off) ? sh[t - off] : 0;
        __syncthreads();
        sh[t] += add;
        __syncthreads();
    }
    if (t < nb) boff[t] = sh[t] - v;
}

__global__ __launch_bounds__(256) void scan_write(
    const int* __restrict__ degi, const int* __restrict__ boff,
    int* __restrict__ row_ptr)
{
    __shared__ int sh[256];
    int t = threadIdx.x;
    int i = blockIdx.x * 256 + t;
    int v = (i < N_NODES) ? degi[i] : 0;
    sh[t] = v;
    __syncthreads();
    for (int off = 1; off < 256; off <<= 1) {
        int add = (t >= off) ? sh[t - off] : 0;
        __syncthreads();
        sh[t] += add;
        __syncthreads();
    }
    if (i < N_NODES) row_ptr[i] = boff[blockIdx.x] + sh[t] - v;
    if (blockIdx.x == 0 && t == 0) row_ptr[N_NODES] = N_EDGES;
}

__global__ __launch_bounds__(256) void fill_kernel(
    const int* __restrict__ src, const int* __restrict__ dst,
    const int* __restrict__ row_ptr, int* __restrict__ cnt,
    int* __restrict__ esrc)
{
    int e = blockIdx.x * blockDim.x + threadIdx.x;
    if (e < N_EDGES) {
        int d = dst[e];
        int p = row_ptr[d] + atomicAdd(&cnt[d], 1);
        esrc[p] = src[e];
    }
}

// ============ weight pre-convert: Wb[layer][j][k] = bf16([Wl | Wr]) ============
__global__ __launch_bounds__(256) void wconv_kernel(
    const float* __restrict__ Wl, const float* __restrict__ Wr,
    unsigned short* __restrict__ Wb)
{
    int idx = blockIdx.x * 256 + threadIdx.x;   // 3*128*256
    if (idx >= 3 * D * K2) return;
    int layer = idx / (D * K2);
    int rem = idx % (D * K2);
    int j = rem / K2;
    int k = rem % K2;
    float v = (k < D) ? Wl[(size_t)layer * D * D + j * D + k]
                      : Wr[(size_t)layer * D * D + j * D + (k - D)];
    Wb[idx] = f2bf(v);
}

// ================= gather aggregation: one wave per node =================
__global__ __launch_bounds__(256) void agg_kernel(
    const float* __restrict__ x, const int* __restrict__ row_ptr,
    const int* __restrict__ esrc, float* __restrict__ mean)
{
    int tid = blockIdx.x * blockDim.x + threadIdx.x;
    int node = tid >> 6;
    int lane = tid & 63;
    if (node >= N_NODES) return;
    int beg = row_ptr[node], end = row_ptr[node + 1];
    float ax = 0.f, ay = 0.f;
    int i = beg;
    for (; i + 4 <= end; i += 4) {
        int s0 = esrc[i], s1 = esrc[i + 1], s2 = esrc[i + 2], s3 = esrc[i + 3];
        float2 v0 = *(const float2*)(x + (size_t)s0 * D + lane * 2);
        float2 v1 = *(const float2*)(x + (size_t)s1 * D + lane * 2);
        float2 v2 = *(const float2*)(x + (size_t)s2 * D + lane * 2);
        float2 v3 = *(const float2*)(x + (size_t)s3 * D + lane * 2);
        ax += v0.x + v1.x + v2.x + v3.x;
        ay += v0.y + v1.y + v2.y + v3.y;
    }
    for (; i < end; ++i) {
        int s = esrc[i];
        float2 v = *(const float2*)(x + (size_t)s * D + lane * 2);
        ax += v.x; ay += v.y;
    }
    float sc = 1.0f / fmaxf((float)(end - beg), 1.0f);
    *(float2*)(mean + (size_t)node * D + lane * 2) = make_float2(ax * sc, ay * sc);
}

// ===== fused MFMA: h = [mean|x] @ Wb^T + bl; LN; ReLU; +res =====
// block = 256 threads (4 waves), MT=32 nodes. out may alias mean or x.
__global__ __launch_bounds__(256) void fused_mfma_kernel(
    const float* __restrict__ x,            // [N,D] layer input (residual source)
    const float* __restrict__ mean,         // [N,D]
    const unsigned short* __restrict__ Wb,  // [D][K2] bf16, this layer
    const float* __restrict__ bl,           // [D]
    const float* __restrict__ gamma_,       // [D]
    const float* __restrict__ beta_,        // [D]
    float* __restrict__ out,                // [N,D]
    int addResidual)
{
    __shared__ unsigned short a_lds[MT * K2];   // 16 KB, XOR-swizzled
    __shared__ float h_s[MT][D + 1];            // 16.5 KB
    __shared__ float mu_s[MT], rs_s[MT];

    int t = threadIdx.x;
    int base = blockIdx.x * MT;

    // ---- stage A = bf16([mean | x]) into swizzled LDS ----
    // 32 rows x 64 float4 = 2048 float4 loads -> 8 per thread, coalesced
#pragma unroll
    for (int it = 0; it < 8; ++it) {
        int idx = it * 256 + t;
        int n = idx >> 6;            // row 0..31
        int c4 = idx & 63;           // float4 index within 256 floats
        int k = c4 * 4;
        int node = base + n;
        const float* srcp = (k < D) ? (mean + (size_t)node * D + k)
                                    : (x + (size_t)node * D + (k - D));
        float4 v = *(const float4*)srcp;
        ushort4 b;
        b.x = f2bf(v.x); b.y = f2bf(v.y); b.z = f2bf(v.z); b.w = f2bf(v.w);
        int byte = n * 512 + k * 2;
        byte ^= ((n & 7) << 4);
        *(ushort4*)((char*)a_lds + byte) = b;
    }
    __syncthreads();

    // ---- MFMA: wave w owns rows (w>>1)*16..+16, cols (w&1)*64..+64 ----
    int w = t >> 6;
    int lane = t & 63;
    int lm = lane & 15;
    int lg = lane >> 4;
    int rowBase = (w >> 1) * 16;
    int colBase = (w & 1) * 64;

    f32x4 acc[4];
#pragma unroll
    for (int c = 0; c < 4; ++c) acc[c] = (f32x4){0.f, 0.f, 0.f, 0.f};

    int arow = rowBase + lm;
    int lin = arow * 512 + lg * 16;     // linear byte address of A frag, + ks*64
    int swz = (arow & 7) << 4;
    const unsigned short* Bp = Wb + (size_t)(colBase + lm) * K2 + lg * 8;
    const char* aB = (const char*)a_lds;

#pragma unroll
    for (int ks = 0; ks < 8; ++ks) {
        bf16x8 a  = *(const bf16x8*)(aB + ((lin + ks * 64) ^ swz));
        bf16x8 b0 = *(const bf16x8*)(Bp + 0 * 16 * K2 + ks * 32);
        bf16x8 b1 = *(const bf16x8*)(Bp + 1 * 16 * K2 + ks * 32);
        bf16x8 b2 = *(const bf16x8*)(Bp + 2 * 16 * K2 + ks * 32);
        bf16x8 b3 = *(const bf16x8*)(Bp + 3 * 16 * K2 + ks * 32);
        acc[0] = __builtin_amdgcn_mfma_f32_16x16x32_bf16(a, b0, acc[0], 0, 0, 0);
        acc[1] = __builtin_amdgcn_mfma_f32_16x16x32_bf16(a, b1, acc[1], 0, 0, 0);
        acc[2] = __builtin_amdgcn_mfma_f32_16x16x32_bf16(a, b2, acc[2], 0, 0, 0);
        acc[3] = __builtin_amdgcn_mfma_f32_16x16x32_bf16(a, b3, acc[3], 0, 0, 0);
    }

    // ---- write h + bias to LDS (D layout: col=lane&15, row=lg*4+reg) ----
    float blv[4];
#pragma unroll
    for (int c = 0; c < 4; ++c) blv[c] = bl[colBase + c * 16 + lm];
#pragma unroll
    for (int c = 0; c < 4; ++c)
#pragma unroll
        for (int r = 0; r < 4; ++r)
            h_s[rowBase + lg * 4 + r][colBase + c * 16 + lm] = acc[c][r] + blv[c];
    __syncthreads();

    // ---- LN stats: 8 threads per row ----
    {
        int n = t >> 3, r = t & 7;
        float s = 0.f, ss = 0.f;
#pragma unroll
        for (int i = 0; i < 16; ++i) {
            float v = h_s[n][r + i * 8];
            s += v; ss += v * v;
        }
#pragma unroll
        for (int m = 4; m >= 1; m >>= 1) {
            s  += __shfl_xor(s,  m, 8);
            ss += __shfl_xor(ss, m, 8);
        }
        if (r == 0) {
            float mu = s * (1.f / 128.f);
            float var = ss * (1.f / 128.f) - mu * mu;
            mu_s[n] = mu;
            rs_s[n] = rsqrtf(var + 1e-5f);
        }
    }
    __syncthreads();

    // ---- normalize + relu + residual ----
#pragma unroll
    for (int it = 0; it < 16; ++it) {
        int idx = it * 256 + t;
        int n = idx >> 7, jj = idx & 127;
        int node = base + n;
        float v = (h_s[n][jj] - mu_s[n]) * rs_s[n] * gamma_[jj] + beta_[jj];
        v = fmaxf(v, 0.f);
        if (addResidual) v += x[(size_t)node * D + jj];
        out[(size_t)node * D + jj] = v;
    }
}

extern "C" void kernel_launch(void* const* d_in, const int* in_sizes, int n_in,
                              void* d_out, int out_size, void* d_ws, size_t ws_size,
                              hipStream_t stream) {
    const float* x0  = (const float*)d_in[0];
    const int*   ei  = (const int*)d_in[1];
    const float* Wl  = (const float*)d_in[2];
    const float* bl  = (const float*)d_in[3];
    const float* Wr  = (const float*)d_in[4];
    const float* gam = (const float*)d_in[5];
    const float* bet = (const float*)d_in[6];
    float* out = (float*)d_out;

    const int* src = ei;
    const int* dst = ei + N_EDGES;

    // ---- workspace layout ----
    int* rp   = (int*)d_ws;            // 100352
    int* cnt  = rp + 100352;           // 100352 (dead after fill -> reused for Wb)
    int* bsum = cnt + 100352;          // 512
    int* boff = bsum + 512;            // 512
    int* esrc = boff + 512;            // 800000
    float* W  = (float*)(esrc + 800000);        // N*D floats
    unsigned short* Wb = (unsigned short*)cnt;  // 3*128*256 bf16 = 192 KB < 401 KB

    const int nbScan = (N_NODES + 255) / 256;
    const int nbEdge = (N_EDGES + 255) / 256;
    const int aggBlocks = (N_NODES * 64 + 255) / 256;
    const int fusedBlocks = N_NODES / MT;       // 3125

    // ---- CSR build ----
    hipMemsetAsync(cnt, 0, N_NODES * sizeof(int), stream);
    hist_kernel<<<nbEdge, 256, 0, stream>>>(dst, cnt);
    scan_reduce<<<nbScan, 256, 0, stream>>>(cnt, bsum);
    scan_bsums<<<1, 512, 0, stream>>>(bsum, boff, nbScan);
    scan_write<<<nbScan, 256, 0, stream>>>(cnt, boff, rp);
    hipMemsetAsync(cnt, 0, N_NODES * sizeof(int), stream);
    fill_kernel<<<nbEdge, 256, 0, stream>>>(src, dst, rp, cnt, esrc);

    // ---- weights -> bf16 (reuses cnt region; cnt is dead now) ----
    wconv_kernel<<<(3 * D * K2 + 255) / 256, 256, 0, stream>>>(Wl, Wr, Wb);

    // ---- layer 0: x0 -> W ----
    agg_kernel<<<aggBlocks, 256, 0, stream>>>(x0, rp, esrc, W);
    fused_mfma_kernel<<<fusedBlocks, 256, 0, stream>>>(
        x0, W, Wb, bl, gam, bet, W, 0);

    // ---- layer 1: W -> out ----
    agg_kernel<<<aggBlocks, 256, 0, stream>>>(W, rp, esrc, out);
    fused_mfma_kernel<<<fusedBlocks, 256, 0, stream>>>(
        W, out, Wb + D * K2, bl + D, gam + D, bet + D, out, 1);

    // ---- layer 2: out -> out (mean in W) ----
    agg_kernel<<<aggBlocks, 256, 0, stream>>>(out, rp, esrc, W);
    fused_mfma_kernel<<<fusedBlocks, 256, 0, stream>>>(
        out, W, Wb + 2 * D * K2, bl + 2 * D, gam + 2 * D, bet + 2 * D, out, 1);
}